// Round 3
// baseline (340.703 us; speedup 1.0000x reference)
//
#include <hip/hip_runtime.h>

typedef __attribute__((ext_vector_type(8))) short short8;
typedef __attribute__((ext_vector_type(4))) float f32x4;

// ---------- bf16 helpers (bit manip, round-to-nearest-even) ----------
__device__ __forceinline__ float bf2f(unsigned short u) {
    union { float f; unsigned u32; } v; v.u32 = ((unsigned)u) << 16; return v.f;
}
__device__ __forceinline__ unsigned short f2bf(float f) {
    union { float f; unsigned u32; } v; v.f = f;
    unsigned x = v.u32;
    x += ((x >> 16) & 1u) + 0x7FFFu;
    return (unsigned short)(x >> 16);
}

// ---------------------------------------------------------------------
// kprep: blocks [0,256): W[4][128][128] -> Wt[head][col][k] bf16.
//        blocks [256,512): W0[512][128] -> W0t[col][k] bf16.
// ---------------------------------------------------------------------
__global__ __launch_bounds__(256) void kprep(const float* __restrict__ W,
                                             const float* __restrict__ W0,
                                             unsigned short* __restrict__ Wt,
                                             unsigned short* __restrict__ W0t) {
    int idx = blockIdx.x * 256 + threadIdx.x;
    if (idx < 65536) {
        int head = idx >> 14, rem = idx & 16383, k = rem >> 7, col = rem & 127;
        Wt[head * 16384 + col * 128 + k] = f2bf(W[idx]);
    } else {
        int i2 = idx - 65536;                 // [0, 65536)
        int k = i2 >> 7, col = i2 & 127;
        W0t[col * 512 + k] = f2bf(W0[i2]);
    }
}

// ---------------------------------------------------------------------
// kgate: g = softmax(h @ Wg). One wave per node.
// ---------------------------------------------------------------------
__global__ __launch_bounds__(256) void kgate(const float* __restrict__ h,
                                             const float* __restrict__ Wg,
                                             float* __restrict__ g,
                                             int N) {
    const int wave = threadIdx.x >> 6;
    const int lane = threadIdx.x & 63;
    const int n = blockIdx.x * 4 + wave;
    if (n >= N) return;

    float2 hv = *(const float2*)&h[(size_t)n * 128 + lane * 2];
    float4 wg0 = *(const float4*)&Wg[(lane * 2) * 4];
    float4 wg1 = *(const float4*)&Wg[(lane * 2 + 1) * 4];
    float z0 = hv.x * wg0.x + hv.y * wg1.x;
    float z1 = hv.x * wg0.y + hv.y * wg1.y;
    float z2 = hv.x * wg0.z + hv.y * wg1.z;
    float z3 = hv.x * wg0.w + hv.y * wg1.w;
    #pragma unroll
    for (int m = 32; m >= 1; m >>= 1) {
        z0 += __shfl_xor(z0, m, 64);
        z1 += __shfl_xor(z1, m, 64);
        z2 += __shfl_xor(z2, m, 64);
        z3 += __shfl_xor(z3, m, 64);
    }
    if (lane == 0) {
        float mx = fmaxf(fmaxf(z0, z1), fmaxf(z2, z3));
        float e0 = __expf(z0 - mx), e1 = __expf(z1 - mx);
        float e2 = __expf(z2 - mx), e3 = __expf(z3 - mx);
        float si = 1.f / (e0 + e1 + e2 + e3);
        float4 gv = make_float4(e0 * si, e1 * si, e2 * si, e3 * si);
        *(float4*)&g[n * 4] = gv;
    }
}

// ---------------------------------------------------------------------
// K1: WH[n, head*128+c] = h[n,:] @ W[head]  via MFMA bf16, all 4 heads per
// block (A tile staged once from f32 h, converted in-stage). Fused s1/s2.
// ---------------------------------------------------------------------
__global__ __launch_bounds__(256) void k1_mfma(const float* __restrict__ h,
                                               const unsigned short* __restrict__ Wt,
                                               const float* __restrict__ a1,
                                               const float* __restrict__ a2,
                                               unsigned short* __restrict__ WH,
                                               float* __restrict__ s1,
                                               float* __restrict__ s2,
                                               int N) {
    __shared__ unsigned short Al[64 * 128];    // 16 KB, swizzled rows of 256 B
    __shared__ unsigned short Bl[128 * 128];   // 32 KB, swizzled rows of 256 B
    const int t = threadIdx.x;
    const int n0 = blockIdx.x * 64;
    const int w = t >> 6, l = t & 63;
    const int l15 = l & 15, lh = l >> 4;

    // stage A from f32 h, converting to bf16
    #pragma unroll
    for (int p = 0; p < 8; ++p) {
        int e = p * 1024 + t * 4;
        int row = e >> 7, col = e & 127;
        float4 v = make_float4(0.f, 0.f, 0.f, 0.f);
        if (n0 + row < N) v = *(const float4*)&h[(size_t)(n0 + row) * 128 + col];
        ushort4 o;
        o.x = f2bf(v.x); o.y = f2bf(v.y); o.z = f2bf(v.z); o.w = f2bf(v.w);
        int byte = row * 256 + col * 2;
        *(ushort4*)((char*)Al + (byte ^ ((row & 7) << 4))) = o;
    }

    for (int head = 0; head < 4; ++head) {
        __syncthreads();
        #pragma unroll
        for (int p = 0; p < 8; ++p) {
            int lin = p * 4096 + t * 16;
            int row = lin >> 8, cb = lin & 255;
            short8 v = *(const short8*)&Wt[(size_t)head * 16384 + row * 128 + (cb >> 1)];
            *(short8*)((char*)Bl + (lin ^ ((row & 7) << 4))) = v;
        }
        __syncthreads();

        f32x4 acc[8] = {};
        const char* Ab = (const char*)Al;
        const char* Bb = (const char*)Bl;
        #pragma unroll
        for (int s = 0; s < 4; ++s) {
            const int arow = w * 16 + l15;
            const int abyte = (arow << 8) + s * 64 + lh * 16;
            short8 af = *(const short8*)(Ab + (abyte ^ ((arow & 7) << 4)));
            #pragma unroll
            for (int cg = 0; cg < 8; ++cg) {
                const int brow = cg * 16 + l15;
                const int bbyte = (brow << 8) + s * 64 + lh * 16;
                short8 bf = *(const short8*)(Bb + (bbyte ^ ((brow & 7) << 4)));
                acc[cg] = __builtin_amdgcn_mfma_f32_16x16x32_bf16(af, bf, acc[cg], 0, 0, 0);
            }
        }

        // epilogue: WH store + fused s1/s2
        float p1[4] = {0.f, 0.f, 0.f, 0.f}, p2[4] = {0.f, 0.f, 0.f, 0.f};
        #pragma unroll
        for (int cg = 0; cg < 8; ++cg) {
            float a1v = a1[head * 128 + cg * 16 + l15];
            float a2v = a2[head * 128 + cg * 16 + l15];
            #pragma unroll
            for (int r = 0; r < 4; ++r) {
                float v = acc[cg][r];
                p1[r] += v * a1v;
                p2[r] += v * a2v;
                int n = n0 + w * 16 + lh * 4 + r;
                if (n < N)
                    WH[(size_t)n * 512 + head * 128 + cg * 16 + l15] = f2bf(v);
            }
        }
        #pragma unroll
        for (int r = 0; r < 4; ++r) {
            #pragma unroll
            for (int m = 8; m >= 1; m >>= 1) {
                p1[r] += __shfl_xor(p1[r], m, 16);
                p2[r] += __shfl_xor(p2[r], m, 16);
            }
        }
        if (l15 == 0) {
            #pragma unroll
            for (int r = 0; r < 4; ++r) {
                int n = n0 + w * 16 + lh * 4 + r;
                if (n < N) { s1[n * 4 + head] = p1[r]; s2[n * 4 + head] = p2[r]; }
            }
        }
    }
}

// ---------------------------------------------------------------------
// K3 fused: 16 nodes/block (4 waves x 4 nodes). Per node: scores + softmax
// (att kept in registers, distributed via shuffles), PV gather -> swizzled
// LDS T-tile. One barrier. Then out[16,128] = Tt @ W0t via MFMA; wave w
// computes col-groups {2w, 2w+1}; B-frags read directly from L2-resident W0t.
// ---------------------------------------------------------------------
__global__ __launch_bounds__(256) void k3_fused(const int* __restrict__ idx,
                                                const unsigned short* __restrict__ WH,
                                                const float* __restrict__ s1,
                                                const float* __restrict__ s2,
                                                const float* __restrict__ g,
                                                const unsigned short* __restrict__ W0t,
                                                float* __restrict__ out,
                                                int N) {
    __shared__ unsigned short Tt[16 * 512];   // 16 KB, swizzled rows of 1024 B
    const int t = threadIdx.x, w = t >> 6, l = t & 63;
    const int d = l & 31, half = l >> 5;
    const int l15 = l & 15, lh = l >> 4;
    const int hsel = l >> 4;
    const int n0 = blockIdx.x * 16;
    const int srcbase = (hsel >= 2) ? 32 : 0;

    for (int i = 0; i < 4; ++i) {
        const int wnode = w * 4 + i;
        int n = n0 + wnode;
        if (n >= N) n = N - 1;                  // clamp (no divergent barrier)

        int j = idx[(size_t)n * 32 + d];
        float2 s2v = *(const float2*)&s2[(size_t)j * 4 + half * 2];
        const float* s1p = &s1[(size_t)n * 4];
        float e0 = s1p[half * 2] + s2v.x;
        float e1 = s1p[half * 2 + 1] + s2v.y;
        e0 = (e0 >= 0.f) ? e0 : 0.01f * e0;
        e1 = (e1 >= 0.f) ? e1 : 0.01f * e1;
        float m0 = e0, m1 = e1;
        #pragma unroll
        for (int mm = 16; mm >= 1; mm >>= 1) {
            m0 = fmaxf(m0, __shfl_xor(m0, mm, 32));
            m1 = fmaxf(m1, __shfl_xor(m1, mm, 32));
        }
        float p0 = __expf(e0 - m0), p1 = __expf(e1 - m1);
        float q0 = p0, q1 = p1;
        #pragma unroll
        for (int mm = 16; mm >= 1; mm >>= 1) {
            q0 += __shfl_xor(q0, mm, 32);
            q1 += __shfl_xor(q1, mm, 32);
        }
        float attv0 = p0 / q0;                  // head half*2,   neighbor d
        float attv1 = p1 / q1;                  // head half*2+1, neighbor d

        // PV gather: full 1KB row per iter; att fetched via 2 shuffles
        const unsigned short* base = WH + (size_t)l * 8;
        float acc0 = 0.f, acc1 = 0.f, acc2 = 0.f, acc3 = 0.f;
        float acc4 = 0.f, acc5 = 0.f, acc6 = 0.f, acc7 = 0.f;
        #pragma unroll
        for (int dd = 0; dd < 32; ++dd) {
            int jj = __shfl(j, dd, 64);
            float a0 = __shfl(attv0, srcbase + dd, 64);
            float a1v = __shfl(attv1, srcbase + dd, 64);
            float a = (hsel & 1) ? a1v : a0;
            short8 v = *(const short8*)(base + (size_t)jj * 512);
            acc0 += a * bf2f((unsigned short)v[0]);
            acc1 += a * bf2f((unsigned short)v[1]);
            acc2 += a * bf2f((unsigned short)v[2]);
            acc3 += a * bf2f((unsigned short)v[3]);
            acc4 += a * bf2f((unsigned short)v[4]);
            acc5 += a * bf2f((unsigned short)v[5]);
            acc6 += a * bf2f((unsigned short)v[6]);
            acc7 += a * bf2f((unsigned short)v[7]);
        }
        float gv = g[(size_t)n * 4 + hsel];
        short8 o;
        o[0] = (short)f2bf(fmaxf(acc0, 0.f) * gv);
        o[1] = (short)f2bf(fmaxf(acc1, 0.f) * gv);
        o[2] = (short)f2bf(fmaxf(acc2, 0.f) * gv);
        o[3] = (short)f2bf(fmaxf(acc3, 0.f) * gv);
        o[4] = (short)f2bf(fmaxf(acc4, 0.f) * gv);
        o[5] = (short)f2bf(fmaxf(acc5, 0.f) * gv);
        o[6] = (short)f2bf(fmaxf(acc6, 0.f) * gv);
        o[7] = (short)f2bf(fmaxf(acc7, 0.f) * gv);
        int byte = wnode * 1024 + l * 16;
        *(short8*)((char*)Tt + (byte ^ ((wnode & 7) << 4))) = o;
    }
    __syncthreads();

    // MFMA epilogue: out[16,128] = Tt(16x512) @ W0t(512x128, stored [col][k])
    // wave w handles col-groups cg in {2w, 2w+1}
    f32x4 oacc[2] = {};
    const char* Ab = (const char*)Tt;
    #pragma unroll
    for (int ks = 0; ks < 16; ++ks) {
        const int abyte = l15 * 1024 + ks * 64 + lh * 16;
        short8 af = *(const short8*)(Ab + (abyte ^ ((l15 & 7) << 4)));
        #pragma unroll
        for (int c = 0; c < 2; ++c) {
            const int cg = w * 2 + c;
            short8 bf = *(const short8*)&W0t[(size_t)(cg * 16 + l15) * 512 + ks * 32 + lh * 8];
            oacc[c] = __builtin_amdgcn_mfma_f32_16x16x32_bf16(af, bf, oacc[c], 0, 0, 0);
        }
    }
    #pragma unroll
    for (int c = 0; c < 2; ++c) {
        const int cg = w * 2 + c;
        #pragma unroll
        for (int r = 0; r < 4; ++r) {
            int n = n0 + lh * 4 + r;
            if (n < N) out[(size_t)n * 128 + cg * 16 + l15] = oacc[c][r];
        }
    }
}

// ---------------------------------------------------------------------
extern "C" void kernel_launch(void* const* d_in, const int* in_sizes, int n_in,
                              void* d_out, int out_size, void* d_ws, size_t ws_size,
                              hipStream_t stream) {
    const float* h     = (const float*)d_in[0];
    const int*   neigh = (const int*)d_in[1];
    const float* W     = (const float*)d_in[2];
    const float* a1    = (const float*)d_in[3];
    const float* a2    = (const float*)d_in[4];
    const float* Wg    = (const float*)d_in[5];
    const float* W0    = (const float*)d_in[6];
    float* out = (float*)d_out;

    const int N = in_sizes[0] / 128;

    char* ws = (char*)d_ws;
    unsigned short* WH = (unsigned short*)ws;                 // N*512 bf16 = N*1024 B
    float* s1 = (float*)(ws + (size_t)N * 1024);              // N*4 f32
    float* s2 = s1 + (size_t)N * 4;
    float* g  = s2 + (size_t)N * 4;
    unsigned short* Wt  = (unsigned short*)(g + (size_t)N * 4);   // 4*128*128 bf16 = 128 KB
    unsigned short* W0t = Wt + 65536;                             // 512*128 bf16 = 128 KB

    kprep<<<dim3(512), dim3(256), 0, stream>>>(W, W0, Wt, W0t);
    kgate<<<dim3((N + 3) / 4), dim3(256), 0, stream>>>(h, Wg, g, N);
    k1_mfma<<<dim3((N + 63) / 64), dim3(256), 0, stream>>>(h, Wt, a1, a2, WH, s1, s2, N);
    k3_fused<<<dim3((N + 15) / 16), dim3(256), 0, stream>>>(neigh, WH, s1, s2, g, W0t, out, N);
}

// Round 4
// 336.637 us; speedup vs baseline: 1.0121x; 1.0121x over previous
//
#include <hip/hip_runtime.h>

typedef __attribute__((ext_vector_type(8))) short short8;
typedef __attribute__((ext_vector_type(4))) float f32x4;

// ---------- bf16 helpers (bit manip, round-to-nearest-even) ----------
__device__ __forceinline__ float bf2f(unsigned short u) {
    union { float f; unsigned u32; } v; v.u32 = ((unsigned)u) << 16; return v.f;
}
__device__ __forceinline__ unsigned short f2bf(float f) {
    union { float f; unsigned u32; } v; v.f = f;
    unsigned x = v.u32;
    x += ((x >> 16) & 1u) + 0x7FFFu;
    return (unsigned short)(x >> 16);
}

// ---------------------------------------------------------------------
// kprep: blocks [0,256): W[4][128][128] -> Wt[head][col][k] bf16.
//        blocks [256,512): W0[512][128] -> W0t[col][k] bf16.
// ---------------------------------------------------------------------
__global__ __launch_bounds__(256) void kprep(const float* __restrict__ W,
                                             const float* __restrict__ W0,
                                             unsigned short* __restrict__ Wt,
                                             unsigned short* __restrict__ W0t) {
    int idx = blockIdx.x * 256 + threadIdx.x;
    if (idx < 65536) {
        int head = idx >> 14, rem = idx & 16383, k = rem >> 7, col = rem & 127;
        Wt[head * 16384 + col * 128 + k] = f2bf(W[idx]);
    } else {
        int i2 = idx - 65536;                 // [0, 65536)
        int k = i2 >> 7, col = i2 & 127;
        W0t[col * 512 + k] = f2bf(W0[i2]);
    }
}

// ---------------------------------------------------------------------
// kgate: g = softmax(h @ Wg). One wave per node.
// ---------------------------------------------------------------------
__global__ __launch_bounds__(256) void kgate(const float* __restrict__ h,
                                             const float* __restrict__ Wg,
                                             float* __restrict__ g,
                                             int N) {
    const int wave = threadIdx.x >> 6;
    const int lane = threadIdx.x & 63;
    const int n = blockIdx.x * 4 + wave;
    if (n >= N) return;

    float2 hv = *(const float2*)&h[(size_t)n * 128 + lane * 2];
    float4 wg0 = *(const float4*)&Wg[(lane * 2) * 4];
    float4 wg1 = *(const float4*)&Wg[(lane * 2 + 1) * 4];
    float z0 = hv.x * wg0.x + hv.y * wg1.x;
    float z1 = hv.x * wg0.y + hv.y * wg1.y;
    float z2 = hv.x * wg0.z + hv.y * wg1.z;
    float z3 = hv.x * wg0.w + hv.y * wg1.w;
    #pragma unroll
    for (int m = 32; m >= 1; m >>= 1) {
        z0 += __shfl_xor(z0, m, 64);
        z1 += __shfl_xor(z1, m, 64);
        z2 += __shfl_xor(z2, m, 64);
        z3 += __shfl_xor(z3, m, 64);
    }
    if (lane == 0) {
        float mx = fmaxf(fmaxf(z0, z1), fmaxf(z2, z3));
        float e0 = __expf(z0 - mx), e1 = __expf(z1 - mx);
        float e2 = __expf(z2 - mx), e3 = __expf(z3 - mx);
        float si = 1.f / (e0 + e1 + e2 + e3);
        float4 gv = make_float4(e0 * si, e1 * si, e2 * si, e3 * si);
        *(float4*)&g[n * 4] = gv;
    }
}

// ---------------------------------------------------------------------
// K1 (no-LDS): one wave per 16 nodes. A-frags from f32 h (inline cvt,
// held across heads); B-frags streamed directly from L2-resident Wt.
// No barriers, no LDS. Fused s1/s2 epilogue.
// ---------------------------------------------------------------------
__global__ __launch_bounds__(256) void k1_nolds(const float* __restrict__ h,
                                                const unsigned short* __restrict__ Wt,
                                                const float* __restrict__ a1,
                                                const float* __restrict__ a2,
                                                unsigned short* __restrict__ WH,
                                                float* __restrict__ s1,
                                                float* __restrict__ s2,
                                                int N) {
    const int t = threadIdx.x, w = t >> 6, l = t & 63;
    const int l15 = l & 15, lh = l >> 4;
    const int n0 = blockIdx.x * 64 + w * 16;     // this wave's 16 nodes
    const int arow = n0 + l15;

    // A-frags: row = l15, k = s*32 + lh*8 + e   (16 VGPR, reused all heads)
    short8 af[4];
    #pragma unroll
    for (int s = 0; s < 4; ++s) {
        float4 v0 = make_float4(0.f, 0.f, 0.f, 0.f);
        float4 v1 = v0;
        if (arow < N) {
            const float* p = &h[(size_t)arow * 128 + s * 32 + lh * 8];
            v0 = *(const float4*)p;
            v1 = *(const float4*)(p + 4);
        }
        short8 a;
        a[0] = (short)f2bf(v0.x); a[1] = (short)f2bf(v0.y);
        a[2] = (short)f2bf(v0.z); a[3] = (short)f2bf(v0.w);
        a[4] = (short)f2bf(v1.x); a[5] = (short)f2bf(v1.y);
        a[6] = (short)f2bf(v1.z); a[7] = (short)f2bf(v1.w);
        af[s] = a;
    }

    for (int head = 0; head < 4; ++head) {
        f32x4 acc[8] = {};
        const unsigned short* Bh = Wt + (size_t)head * 16384;
        #pragma unroll
        for (int s = 0; s < 4; ++s) {
            #pragma unroll
            for (int cg = 0; cg < 8; ++cg) {
                short8 bf = *(const short8*)&Bh[(size_t)(cg * 16 + l15) * 128 + s * 32 + lh * 8];
                acc[cg] = __builtin_amdgcn_mfma_f32_16x16x32_bf16(af[s], bf, acc[cg], 0, 0, 0);
            }
        }

        // epilogue: WH store + fused s1/s2
        float p1[4] = {0.f, 0.f, 0.f, 0.f}, p2[4] = {0.f, 0.f, 0.f, 0.f};
        #pragma unroll
        for (int cg = 0; cg < 8; ++cg) {
            float a1v = a1[head * 128 + cg * 16 + l15];
            float a2v = a2[head * 128 + cg * 16 + l15];
            #pragma unroll
            for (int r = 0; r < 4; ++r) {
                float v = acc[cg][r];
                p1[r] += v * a1v;
                p2[r] += v * a2v;
                int n = n0 + lh * 4 + r;
                if (n < N)
                    WH[(size_t)n * 512 + head * 128 + cg * 16 + l15] = f2bf(v);
            }
        }
        #pragma unroll
        for (int r = 0; r < 4; ++r) {
            #pragma unroll
            for (int m = 8; m >= 1; m >>= 1) {
                p1[r] += __shfl_xor(p1[r], m, 16);
                p2[r] += __shfl_xor(p2[r], m, 16);
            }
        }
        if (l15 == 0) {
            #pragma unroll
            for (int r = 0; r < 4; ++r) {
                int n = n0 + lh * 4 + r;
                if (n < N) { s1[n * 4 + head] = p1[r]; s2[n * 4 + head] = p2[r]; }
            }
        }
    }
}

// ---------------------------------------------------------------------
// K3 fused v2: 512 thr = 8 waves = 8 nodes (1 node/wave, round-2 gather
// structure: att via LDS broadcast, fully-unrolled 32-deep gather).
// PV -> 16-row swizzled LDS tile (rows 8..15 zeroed); one barrier; MFMA
// epilogue: wave w computes col-group w of out = T @ W0t, B-frags from
// L2-resident W0t.
// ---------------------------------------------------------------------
__global__ __launch_bounds__(512) void k3_fused(const int* __restrict__ idx,
                                                const unsigned short* __restrict__ WH,
                                                const float* __restrict__ s1,
                                                const float* __restrict__ s2,
                                                const float* __restrict__ g,
                                                const unsigned short* __restrict__ W0t,
                                                float* __restrict__ out,
                                                int N) {
    __shared__ unsigned short Tt[16 * 512];   // 16 KB, swizzled rows of 1024 B
    __shared__ float att[8][4][33];
    const int t = threadIdx.x, w = t >> 6, l = t & 63;
    const int d = l & 31, half = l >> 5;
    const int l15 = l & 15, lh = l >> 4;
    const int hsel = l >> 4;
    const int n0 = blockIdx.x * 8;

    // zero pad rows 8..15 (read by MFMA A-frags, discarded at store)
    *(short8*)((char*)Tt + 8192 + t * 16) = short8{};

    int n = n0 + w;
    const bool valid = (n < N);
    if (!valid) n = N - 1;

    // scores + softmax (2 heads per lane via half split)
    int j = idx[(size_t)n * 32 + d];
    float2 s2v = *(const float2*)&s2[(size_t)j * 4 + half * 2];
    const float* s1p = &s1[(size_t)n * 4];
    float e0 = s1p[half * 2] + s2v.x;
    float e1 = s1p[half * 2 + 1] + s2v.y;
    e0 = (e0 >= 0.f) ? e0 : 0.01f * e0;
    e1 = (e1 >= 0.f) ? e1 : 0.01f * e1;
    float m0 = e0, m1 = e1;
    #pragma unroll
    for (int mm = 16; mm >= 1; mm >>= 1) {
        m0 = fmaxf(m0, __shfl_xor(m0, mm, 32));
        m1 = fmaxf(m1, __shfl_xor(m1, mm, 32));
    }
    float p0 = __expf(e0 - m0), p1 = __expf(e1 - m1);
    float q0 = p0, q1 = p1;
    #pragma unroll
    for (int mm = 16; mm >= 1; mm >>= 1) {
        q0 += __shfl_xor(q0, mm, 32);
        q1 += __shfl_xor(q1, mm, 32);
    }
    att[w][half * 2][d] = p0 / q0;
    att[w][half * 2 + 1][d] = p1 / q1;

    // PV gather: full 1KB row per iter; att from LDS (broadcast per 16-lane
    // group); j broadcast via shuffle. 8 independent accumulators.
    const unsigned short* base = WH + (size_t)l * 8;
    float acc0 = 0.f, acc1 = 0.f, acc2 = 0.f, acc3 = 0.f;
    float acc4 = 0.f, acc5 = 0.f, acc6 = 0.f, acc7 = 0.f;
    #pragma unroll
    for (int dd = 0; dd < 32; ++dd) {
        int jj = __shfl(j, dd, 64);
        float a = att[w][hsel][dd];
        short8 v = *(const short8*)(base + (size_t)jj * 512);
        acc0 += a * bf2f((unsigned short)v[0]);
        acc1 += a * bf2f((unsigned short)v[1]);
        acc2 += a * bf2f((unsigned short)v[2]);
        acc3 += a * bf2f((unsigned short)v[3]);
        acc4 += a * bf2f((unsigned short)v[4]);
        acc5 += a * bf2f((unsigned short)v[5]);
        acc6 += a * bf2f((unsigned short)v[6]);
        acc7 += a * bf2f((unsigned short)v[7]);
    }
    float gv = g[(size_t)n * 4 + hsel];
    short8 o;
    o[0] = (short)f2bf(fmaxf(acc0, 0.f) * gv);
    o[1] = (short)f2bf(fmaxf(acc1, 0.f) * gv);
    o[2] = (short)f2bf(fmaxf(acc2, 0.f) * gv);
    o[3] = (short)f2bf(fmaxf(acc3, 0.f) * gv);
    o[4] = (short)f2bf(fmaxf(acc4, 0.f) * gv);
    o[5] = (short)f2bf(fmaxf(acc5, 0.f) * gv);
    o[6] = (short)f2bf(fmaxf(acc6, 0.f) * gv);
    o[7] = (short)f2bf(fmaxf(acc7, 0.f) * gv);
    {
        int byte = w * 1024 + l * 16;
        *(short8*)((char*)Tt + (byte ^ ((w & 7) << 4))) = o;
    }
    __syncthreads();

    // MFMA epilogue: out[8,128] = Tt(16x512, 8 valid) @ W0t(512x128 [col][k]).
    // wave w -> col-group w (16 cols), full K = 512 (16 MFMAs).
    const int cg = w;
    f32x4 oacc = {};
    const char* Ab = (const char*)Tt;
    #pragma unroll
    for (int ks = 0; ks < 16; ++ks) {
        const int abyte = l15 * 1024 + ks * 64 + lh * 16;
        short8 afr = *(const short8*)(Ab + (abyte ^ ((l15 & 7) << 4)));
        short8 bfr = *(const short8*)&W0t[(size_t)(cg * 16 + l15) * 512 + ks * 32 + lh * 8];
        oacc = __builtin_amdgcn_mfma_f32_16x16x32_bf16(afr, bfr, oacc, 0, 0, 0);
    }
    #pragma unroll
    for (int r = 0; r < 4; ++r) {
        int row = lh * 4 + r;
        if (row < 8) {
            int nn = n0 + row;
            if (nn < N) out[(size_t)nn * 128 + cg * 16 + l15] = oacc[r];
        }
    }
}

// ---------------------------------------------------------------------
extern "C" void kernel_launch(void* const* d_in, const int* in_sizes, int n_in,
                              void* d_out, int out_size, void* d_ws, size_t ws_size,
                              hipStream_t stream) {
    const float* h     = (const float*)d_in[0];
    const int*   neigh = (const int*)d_in[1];
    const float* W     = (const float*)d_in[2];
    const float* a1    = (const float*)d_in[3];
    const float* a2    = (const float*)d_in[4];
    const float* Wg    = (const float*)d_in[5];
    const float* W0    = (const float*)d_in[6];
    float* out = (float*)d_out;

    const int N = in_sizes[0] / 128;

    char* ws = (char*)d_ws;
    unsigned short* WH = (unsigned short*)ws;                 // N*512 bf16 = N*1024 B
    float* s1 = (float*)(ws + (size_t)N * 1024);              // N*4 f32
    float* s2 = s1 + (size_t)N * 4;
    float* g  = s2 + (size_t)N * 4;
    unsigned short* Wt  = (unsigned short*)(g + (size_t)N * 4);   // 4*128*128 bf16 = 128 KB
    unsigned short* W0t = Wt + 65536;                             // 512*128 bf16 = 128 KB

    kprep<<<dim3(512), dim3(256), 0, stream>>>(W, W0, Wt, W0t);
    kgate<<<dim3((N + 3) / 4), dim3(256), 0, stream>>>(h, Wg, g, N);
    k1_nolds<<<dim3((N + 63) / 64), dim3(256), 0, stream>>>(h, Wt, a1, a2, WH, s1, s2, N);
    k3_fused<<<dim3((N + 7) / 8), dim3(512), 0, stream>>>(neigh, WH, s1, s2, g, W0t, out, N);
}

// Round 5
// 191.725 us; speedup vs baseline: 1.7770x; 1.7558x over previous
//
#include <hip/hip_runtime.h>

typedef __attribute__((ext_vector_type(8))) short short8;
typedef __attribute__((ext_vector_type(4))) float f32x4;

// ---------- bf16 helpers (bit manip, round-to-nearest-even) ----------
__device__ __forceinline__ float bf2f(unsigned u16) {
    union { float f; unsigned u32; } v; v.u32 = u16 << 16; return v.f;
}
__device__ __forceinline__ unsigned short f2bf(float f) {
    union { float f; unsigned u32; } v; v.f = f;
    unsigned x = v.u32;
    x += ((x >> 16) & 1u) + 0x7FFFu;
    return (unsigned short)(x >> 16);
}

// ---------------------------------------------------------------------
// kprep: blocks [0,256): W[4][128][128] -> Wt[head][col][k] bf16.
//        blocks [256,512): W0[512][128] -> W0t[col][k] bf16.
//        blocks [512,514): b1[k][i] = W[k][i][:].a1[k], b2 likewise (f32).
// ---------------------------------------------------------------------
__global__ __launch_bounds__(256) void kprep(const float* __restrict__ W,
                                             const float* __restrict__ W0,
                                             const float* __restrict__ a1,
                                             const float* __restrict__ a2,
                                             unsigned short* __restrict__ Wt,
                                             unsigned short* __restrict__ W0t,
                                             float* __restrict__ b1,
                                             float* __restrict__ b2) {
    int b = blockIdx.x, t = threadIdx.x;
    if (b < 256) {
        int idx = b * 256 + t;
        int head = idx >> 14, rem = idx & 16383, k = rem >> 7, col = rem & 127;
        Wt[head * 16384 + col * 128 + k] = f2bf(W[idx]);
    } else if (b < 512) {
        int i2 = (b - 256) * 256 + t;
        int k = i2 >> 7, col = i2 & 127;
        W0t[col * 512 + k] = f2bf(W0[i2]);
    } else {
        int idx = (b - 512) * 256 + t;          // [0, 512)
        int k = idx >> 7, i = idx & 127;
        const float* wr = &W[k * 16384 + i * 128];
        const float* A1 = &a1[k * 128];
        const float* A2 = &a2[k * 128];
        float v1 = 0.f, v2 = 0.f;
        for (int c = 0; c < 128; ++c) { float wv = wr[c]; v1 += wv * A1[c]; v2 += wv * A2[c]; }
        b1[k * 128 + i] = v1;
        b2[k * 128 + i] = v2;
    }
}

// ---------------------------------------------------------------------
// kscore: per node (1 wave): hb = bf16(h); s1[n,k]=h.b1[k]; s2[n,k]=h.b2[k];
// g = softmax(h @ Wg). All from one read of h.
// ---------------------------------------------------------------------
__global__ __launch_bounds__(256) void kscore(const float* __restrict__ h,
                                              const float* __restrict__ Wg,
                                              const float* __restrict__ b1,
                                              const float* __restrict__ b2,
                                              unsigned* __restrict__ hb32,
                                              float* __restrict__ s1,
                                              float* __restrict__ s2,
                                              float* __restrict__ g,
                                              int N) {
    const int wave = threadIdx.x >> 6, lane = threadIdx.x & 63;
    const int n = blockIdx.x * 4 + wave;
    if (n >= N) return;

    float2 hv = *(const float2*)&h[(size_t)n * 128 + lane * 2];
    hb32[(size_t)n * 64 + lane] = (unsigned)f2bf(hv.x) | ((unsigned)f2bf(hv.y) << 16);

    float p[12];
    float4 wg0 = *(const float4*)&Wg[(lane * 2) * 4];
    float4 wg1 = *(const float4*)&Wg[(lane * 2 + 1) * 4];
    p[8]  = hv.x * wg0.x + hv.y * wg1.x;
    p[9]  = hv.x * wg0.y + hv.y * wg1.y;
    p[10] = hv.x * wg0.z + hv.y * wg1.z;
    p[11] = hv.x * wg0.w + hv.y * wg1.w;
    #pragma unroll
    for (int k = 0; k < 4; ++k) {
        float2 bv1 = *(const float2*)&b1[k * 128 + lane * 2];
        float2 bv2 = *(const float2*)&b2[k * 128 + lane * 2];
        p[k]     = hv.x * bv1.x + hv.y * bv1.y;
        p[4 + k] = hv.x * bv2.x + hv.y * bv2.y;
    }
    #pragma unroll
    for (int m = 32; m >= 1; m >>= 1) {
        #pragma unroll
        for (int i = 0; i < 12; ++i) p[i] += __shfl_xor(p[i], m, 64);
    }
    if (lane == 0) {
        *(float4*)&s1[n * 4] = make_float4(p[0], p[1], p[2], p[3]);
        *(float4*)&s2[n * 4] = make_float4(p[4], p[5], p[6], p[7]);
        float mx = fmaxf(fmaxf(p[8], p[9]), fmaxf(p[10], p[11]));
        float e0 = __expf(p[8] - mx), e1 = __expf(p[9] - mx);
        float e2 = __expf(p[10] - mx), e3 = __expf(p[11] - mx);
        float si = 1.f / (e0 + e1 + e2 + e3);
        *(float4*)&g[n * 4] = make_float4(e0 * si, e1 * si, e2 * si, e3 * si);
    }
}

// ---------------------------------------------------------------------
// k3_mix: one node per wave (4/block). Scores + softmax (per-head att ->
// LDS float4 per neighbor), then gather h_bf16[j] (256 B/row: 1 dword/lane)
// and accumulate mixed_k = sum_d att_k[d] * h[j_d] in f32.
// Store Mixed[n, k*128+c] bf16.   No barriers; wave-local LDS only.
// ---------------------------------------------------------------------
__global__ __launch_bounds__(256) void k3_mix(const int* __restrict__ idx,
                                              const unsigned* __restrict__ hb32,
                                              const float* __restrict__ s1,
                                              const float* __restrict__ s2,
                                              unsigned* __restrict__ Mx32,
                                              int N) {
    __shared__ float att4s[4][32][4];
    const int t = threadIdx.x, w = t >> 6, l = t & 63;
    const int d = l & 31, half = l >> 5;
    int n = blockIdx.x * 4 + w;
    const bool valid = (n < N);
    if (!valid) n = N - 1;

    // scores + softmax: lane (half,d) handles heads {2*half, 2*half+1}
    int j = idx[(size_t)n * 32 + d];
    float2 s2v = *(const float2*)&s2[(size_t)j * 4 + half * 2];
    const float* s1p = &s1[(size_t)n * 4];
    float e0 = s1p[half * 2] + s2v.x;
    float e1 = s1p[half * 2 + 1] + s2v.y;
    e0 = (e0 >= 0.f) ? e0 : 0.01f * e0;
    e1 = (e1 >= 0.f) ? e1 : 0.01f * e1;
    float m0 = e0, m1 = e1;
    #pragma unroll
    for (int mm = 16; mm >= 1; mm >>= 1) {
        m0 = fmaxf(m0, __shfl_xor(m0, mm, 32));
        m1 = fmaxf(m1, __shfl_xor(m1, mm, 32));
    }
    float p0 = __expf(e0 - m0), p1 = __expf(e1 - m1);
    float q0 = p0, q1 = p1;
    #pragma unroll
    for (int mm = 16; mm >= 1; mm >>= 1) {
        q0 += __shfl_xor(q0, mm, 32);
        q1 += __shfl_xor(q1, mm, 32);
    }
    *(float2*)&att4s[w][d][half * 2] = make_float2(p0 / q0, p1 / q1);

    // gather h rows, accumulate 4-head weighted sums; lane owns cols {2l,2l+1}
    float ac[4][2] = {};
    #pragma unroll
    for (int dd = 0; dd < 32; ++dd) {
        int jj = __shfl(j, dd, 64);
        unsigned hv = hb32[(size_t)jj * 64 + l];
        float h0 = bf2f(hv & 0xffffu);
        float h1 = bf2f(hv >> 16);
        float4 a4 = *(const float4*)&att4s[w][dd][0];
        ac[0][0] += a4.x * h0; ac[0][1] += a4.x * h1;
        ac[1][0] += a4.y * h0; ac[1][1] += a4.y * h1;
        ac[2][0] += a4.z * h0; ac[2][1] += a4.z * h1;
        ac[3][0] += a4.w * h0; ac[3][1] += a4.w * h1;
    }
    if (valid) {
        #pragma unroll
        for (int k = 0; k < 4; ++k) {
            unsigned pk = (unsigned)f2bf(ac[k][0]) | ((unsigned)f2bf(ac[k][1]) << 16);
            Mx32[(size_t)n * 256 + k * 64 + l] = pk;
        }
    }
}

// ---------------------------------------------------------------------
// k4_gemm: per 64-node tile: U_k = relu(Mixed_k @ W_k) * g_k  (wave w ->
// head w, in-place in the LDS Mixed tile, per-wave col-slice discipline),
// then out = U @ W0t (wave w -> rows 16w..16w+15, B from L2-resident W0t).
// ---------------------------------------------------------------------
__global__ __launch_bounds__(256) void k4_gemm(const unsigned short* __restrict__ Mx,
                                               const unsigned short* __restrict__ Wt,
                                               const unsigned short* __restrict__ W0t,
                                               const float* __restrict__ g,
                                               float* __restrict__ out,
                                               int N) {
    __shared__ unsigned short U[64 * 512];    // 64 KB, swizzled rows of 1024 B
    __shared__ float gld[64][4];
    const int t = threadIdx.x, w = t >> 6, l = t & 63;
    const int l15 = l & 15, lh = l >> 4;
    const int n0 = blockIdx.x * 64;

    // stage Mixed tile
    #pragma unroll
    for (int p = 0; p < 16; ++p) {
        int lin = p * 4096 + t * 16;
        int row = lin >> 10, cb = lin & 1023;
        short8 v = {};
        if (n0 + row < N) v = *(const short8*)&Mx[(size_t)(n0 + row) * 512 + (cb >> 1)];
        *(short8*)((char*)U + (lin ^ ((row & 7) << 4))) = v;
    }
    if (t < 64) {
        float4 gv = make_float4(0.f, 0.f, 0.f, 0.f);
        if (n0 + t < N) gv = *(const float4*)&g[(size_t)(n0 + t) * 4];
        *(float4*)gld[t] = gv;
    }
    __syncthreads();

    // phase 1: head-GEMM; wave w computes head w, overwrites its col-slice
    const char* Ub = (const char*)U;
    for (int rg = 0; rg < 4; ++rg) {
        short8 af[4];
        #pragma unroll
        for (int s = 0; s < 4; ++s) {
            int arow = rg * 16 + l15;
            int ab = arow * 1024 + w * 256 + s * 64 + lh * 16;
            af[s] = *(const short8*)(Ub + (ab ^ ((arow & 7) << 4)));
        }
        f32x4 acc[8] = {};
        #pragma unroll
        for (int s = 0; s < 4; ++s) {
            #pragma unroll
            for (int cg = 0; cg < 8; ++cg) {
                short8 bf = *(const short8*)&Wt[(size_t)w * 16384 + (cg * 16 + l15) * 128 + s * 32 + lh * 8];
                acc[cg] = __builtin_amdgcn_mfma_f32_16x16x32_bf16(af[s], bf, acc[cg], 0, 0, 0);
            }
        }
        #pragma unroll
        for (int cg = 0; cg < 8; ++cg) {
            #pragma unroll
            for (int r = 0; r < 4; ++r) {
                int row = rg * 16 + lh * 4 + r;
                float v = fmaxf(acc[cg][r], 0.f) * gld[row][w];
                int ub = row * 1024 + w * 256 + (cg * 16 + l15) * 2;
                *(unsigned short*)((char*)U + (ub ^ ((row & 7) << 4))) = f2bf(v);
            }
        }
    }
    __syncthreads();

    // phase 2: out = U @ W0t; wave w -> rows w*16..w*16+15
    f32x4 oacc[8] = {};
    #pragma unroll
    for (int ks = 0; ks < 16; ++ks) {
        const int arow = w * 16 + l15;
        const int ab = arow * 1024 + ks * 64 + lh * 16;
        short8 afr = *(const short8*)(Ub + (ab ^ ((arow & 7) << 4)));
        #pragma unroll
        for (int cg = 0; cg < 8; ++cg) {
            short8 bfr = *(const short8*)&W0t[(size_t)(cg * 16 + l15) * 512 + ks * 32 + lh * 8];
            oacc[cg] = __builtin_amdgcn_mfma_f32_16x16x32_bf16(afr, bfr, oacc[cg], 0, 0, 0);
        }
    }
    #pragma unroll
    for (int cg = 0; cg < 8; ++cg) {
        #pragma unroll
        for (int r = 0; r < 4; ++r) {
            int n = n0 + w * 16 + lh * 4 + r;
            if (n < N) out[(size_t)n * 128 + cg * 16 + l15] = oacc[cg][r];
        }
    }
}

// ---------------------------------------------------------------------
extern "C" void kernel_launch(void* const* d_in, const int* in_sizes, int n_in,
                              void* d_out, int out_size, void* d_ws, size_t ws_size,
                              hipStream_t stream) {
    const float* h     = (const float*)d_in[0];
    const int*   neigh = (const int*)d_in[1];
    const float* W     = (const float*)d_in[2];
    const float* a1    = (const float*)d_in[3];
    const float* a2    = (const float*)d_in[4];
    const float* Wg    = (const float*)d_in[5];
    const float* W0    = (const float*)d_in[6];
    float* out = (float*)d_out;

    const int N = in_sizes[0] / 128;

    char* ws = (char*)d_ws;
    unsigned* hb32 = (unsigned*)ws;                                  // N*64 u32 (h bf16)
    unsigned* Mx32 = (unsigned*)(ws + (size_t)N * 256);              // N*256 u32 (Mixed bf16)
    float* s1 = (float*)(ws + (size_t)N * 256 + (size_t)N * 1024);   // N*4 f32
    float* s2 = s1 + (size_t)N * 4;
    float* g  = s2 + (size_t)N * 4;
    unsigned short* Wt  = (unsigned short*)(g + (size_t)N * 4);      // 128 KB
    unsigned short* W0t = Wt + 65536;                                // 128 KB
    float* b1 = (float*)(W0t + 65536);                               // 2 KB
    float* b2 = b1 + 512;                                            // 2 KB

    kprep<<<dim3(514), dim3(256), 0, stream>>>(W, W0, a1, a2, Wt, W0t, b1, b2);
    kscore<<<dim3((N + 3) / 4), dim3(256), 0, stream>>>(h, Wg, b1, b2, hb32, s1, s2, g, N);
    k3_mix<<<dim3((N + 3) / 4), dim3(256), 0, stream>>>(neigh, hb32, s1, s2, Mx32, N);
    k4_gemm<<<dim3((N + 63) / 64), dim3(256), 0, stream>>>((const unsigned short*)Mx32, Wt, W0t, g,
                                                           out, N);
}